// Round 3
// baseline (174.208 us; speedup 1.0000x reference)
//
#include <hip/hip_runtime.h>
#include <math.h>

#define DD   128
#define DI   170
#define DIP4 43                     // ceil(DI/4), padded i-quads
#define BB   4096
#define NNEG 5
#define ROWS 8
#define NBLK (BB / ROWS)            // 512 blocks -> 2 blocks/CU
#define TASKS (ROWS * (1 + NNEG))   // 48 logit tasks per block
#define TPW  (TASKS / 4)            // 12 per wave
#define SQRT_D 11.3137084989847603904f   // sqrt(128)

__device__ __forceinline__ float wave_bcast_sum(float v) {
#pragma unroll
    for (int m = 1; m < 64; m <<= 1) v += __shfl_xor(v, m, 64);
    return v;
}

// Prep kernel (108 blocks):
//  blocks 0..84  : row norms of W_hidden/W_gate (340 rows, 1 wave each) AND
//                  transpose-write the row into WhT4/WgT4 = [32][DI] float4
//                  (K-quad packed: element [d4][i] = W[i][4d4..4d4+3]) --
//                  the wave already holds the row in registers, so the
//                  transpose is one extra float2 store per lane.
//  block 85      : inv_f (W_ff_out column norms, coalesced row-walk) + zero out.
//  blocks 86..107: WfT4 = [DIP4][DD] float4, element [i4][dd] =
//                  W_ff_out[dd][4i4..4i4+3], zero-padded past i=169
//                  (ws is re-poisoned 0xAA before every launch).
__global__ __launch_bounds__(256) void prep_kernel(
    const float* __restrict__ W_hidden,
    const float* __restrict__ W_gate,
    const float* __restrict__ W_ff_out,
    float* __restrict__ whT,
    float* __restrict__ wgT,
    float* __restrict__ wfT,
    float* __restrict__ inv_h,
    float* __restrict__ inv_g,
    float* __restrict__ inv_f,
    float* __restrict__ out)
{
    const int blk = blockIdx.x;
    if (blk < 85) {
        const int wave = threadIdx.x >> 6;
        const int lane = threadIdx.x & 63;
        const int v = blk * 4 + wave;                 // 0 .. 339
        const float* W = (v < DI) ? W_hidden : W_gate;
        float*       T = (v < DI) ? whT : wgT;
        const int  row = (v < DI) ? v : v - DI;
        float2 p = ((const float2*)(W + (long)row * DD))[lane];   // d = 2*lane, 2*lane+1
        // transpose write: d4 = lane>>1, half = lane&1
        ((float2*)(T + (((lane >> 1) * DI + row) << 2)))[lane & 1] = p;
        float s = wave_bcast_sum(p.x * p.x + p.y * p.y);
        if (lane == 0) {
            float inv = rsqrtf(s);
            if (v < DI) inv_h[row] = inv; else inv_g[row] = inv;
        }
    } else if (blk == 85) {
        if (threadIdx.x == 0) out[0] = 0.0f;
        const int c = threadIdx.x;                    // column of W_ff_out (D x DI)
        if (c < DI) {
            float s = 0.0f;
#pragma unroll 4
            for (int d = 0; d < DD; ++d) {
                float a = W_ff_out[(long)d * DI + c]; // coalesced across threads
                s += a * a;
            }
            inv_f[c] = rsqrtf(s);
        }
    } else {
        const int t = (blk - 86) * 256 + threadIdx.x; // 0 .. 5631, need DIP4*DD=5504
        if (t < DIP4 * DD) {
            const int dd = t / DIP4;                  // consecutive t walks i4: coalesced reads
            const int i4 = t - dd * DIP4;
            const float* src = W_ff_out + (long)dd * DI;
            float4 v4;
            const int i = 4 * i4;
            v4.x = (i + 0 < DI) ? src[i + 0] : 0.0f;
            v4.y = (i + 1 < DI) ? src[i + 1] : 0.0f;
            v4.z = (i + 2 < DI) ? src[i + 2] : 0.0f;
            v4.w = (i + 3 < DI) ? src[i + 3] : 0.0f;
            ((float4*)wfT)[i4 * DD + dd] = v4;
        }
    }
}

__global__ __launch_bounds__(256) void main_kernel(
    const int*   __restrict__ input_ids,
    const int*   __restrict__ target_ids,
    const int*   __restrict__ neg_ids,
    const float* __restrict__ W_in,
    const float* __restrict__ W_out,
    const float* __restrict__ whT,
    const float* __restrict__ wgT,
    const float* __restrict__ wfT,
    const float* __restrict__ hidden_scale,
    const float* __restrict__ gate_scale,
    const float* __restrict__ logit_scale,
    const float* __restrict__ inv_h,
    const float* __restrict__ inv_g,
    const float* __restrict__ inv_f,
    float* __restrict__ out)
{
    __shared__ __align__(16) float s_emb[ROWS][DD];     // 4 KB
    __shared__ __align__(16) float s_x[ROWS][4 * DIP4]; // 8 x 172, rows 16B-aligned
    __shared__ __align__(16) float s_xout[ROWS][DD];    // 4 KB
    __shared__ float s_red[4];

    const int tid  = threadIdx.x;
    const int wave = tid >> 6;
    const int lane = tid & 63;
    const int b0   = blockIdx.x * ROWS;

    // ---- Phase 1: gather + l2-normalize input embeddings into LDS ----
#pragma unroll
    for (int k = 0; k < ROWS / 4; ++k) {
        const int r  = wave + 4 * k;
        const int id = input_ids[b0 + r];
        float2 p = ((const float2*)(W_in + (long)id * DD))[lane];
        float s  = wave_bcast_sum(p.x * p.x + p.y * p.y);
        float inv = rsqrtf(s);
        s_emb[r][2 * lane]     = p.x * inv;
        s_emb[r][2 * lane + 1] = p.y * inv;
    }
    __syncthreads();

    // ---- Phase 2: h = (emb @ l2n(Wh).T)*hs ; g = (emb @ l2n(Wg).T)*gs*sqrt(D)
    //      x = silu(g)*h, fold in W_ff_out column inv-norm.
    //      Weight loads from transposed copies: lane i reads contiguous 16B. ----
    if (tid < DI) {
        const int i = tid;
        float ah[ROWS], ag[ROWS];
#pragma unroll
        for (int r = 0; r < ROWS; ++r) { ah[r] = 0.0f; ag[r] = 0.0f; }
        const float4* wh4 = (const float4*)whT;   // [32][DI]
        const float4* wg4 = (const float4*)wgT;
#pragma unroll 4
        for (int d4 = 0; d4 < DD / 4; ++d4) {
            float4 h4 = wh4[d4 * DI + i];         // coalesced across lanes
            float4 g4 = wg4[d4 * DI + i];
#pragma unroll
            for (int r = 0; r < ROWS; ++r) {
                float4 e4 = ((const float4*)s_emb[r])[d4];   // broadcast
                ah[r] += e4.x * h4.x + e4.y * h4.y + e4.z * h4.z + e4.w * h4.w;
                ag[r] += e4.x * g4.x + e4.y * g4.y + e4.z * g4.z + e4.w * g4.w;
            }
        }
        const float hs = hidden_scale[i] * inv_h[i];
        const float gs = gate_scale[i]   * inv_g[i] * SQRT_D;
        const float fi = inv_f[i];
#pragma unroll
        for (int r = 0; r < ROWS; ++r) {
            float h = ah[r] * hs;
            float g = ag[r] * gs;
            float x = (g / (1.0f + __expf(-g))) * h;   // silu(g) * h
            s_x[r][i] = x * fi;
        }
    } else if (tid < 4 * DIP4) {                   // zero the i=170..171 pad
#pragma unroll
        for (int r = 0; r < ROWS; ++r) s_x[r][tid] = 0.0f;
    }
    __syncthreads();

    // ---- Phase 2b: xout[r][dd] = sum_i s_x[r][i] * W_ff_out[dd][i]
    //      via WfT4 [i4][dd]: coalesced across lanes. ----
    {
        const int dd = tid & 127;
        const int r0 = tid >> 7;    // 0 or 1, wave-uniform
        float acc[ROWS / 2];
#pragma unroll
        for (int k = 0; k < ROWS / 2; ++k) acc[k] = 0.0f;
        const float4* wf4 = (const float4*)wfT;   // [DIP4][DD]
#pragma unroll 4
        for (int i4 = 0; i4 < DIP4; ++i4) {
            float4 wf = wf4[i4 * DD + dd];
#pragma unroll
            for (int k = 0; k < ROWS / 2; ++k) {
                const int r = r0 + 2 * k;
                float4 xv = *(const float4*)&s_x[r][4 * i4];   // broadcast
                acc[k] += xv.x * wf.x + xv.y * wf.y + xv.z * wf.z + xv.w * wf.w;
            }
        }
#pragma unroll
        for (int k = 0; k < ROWS / 2; ++k) s_xout[r0 + 2 * k][dd] = acc[k];
    }
    __syncthreads();

    // ---- Phase 3: gathered logits + negative-sampling loss.
    //      Load phase first (all 12 W_out row-halves in flight), then reduce. ----
    float dotp[TPW], ssp[TPW], lsc[TPW];
    const int tbase = wave * TPW;
#pragma unroll
    for (int k = 0; k < TPW; ++k) {
        const int t  = tbase + k;
        const int r  = t / (1 + NNEG);
        const int jj = t % (1 + NNEG);
        const int bidx = b0 + r;
        const int id = (jj == 0) ? target_ids[bidx] : neg_ids[bidx * NNEG + jj - 1];
        const float* wrow = W_out + (long)id * DD;
        float w0 = wrow[lane], w1 = wrow[64 + lane];
        float x0 = s_xout[r][lane], x1 = s_xout[r][64 + lane];
        dotp[k] = w0 * x0 + w1 * x1;
        ssp[k]  = w0 * w0 + w1 * w1;
        lsc[k]  = logit_scale[id];
    }
    float wacc = 0.0f;
#pragma unroll
    for (int k = 0; k < TPW; ++k) {
        float dot = dotp[k], ss = ssp[k];
#pragma unroll
        for (int m = 1; m < 64; m <<= 1) {
            dot += __shfl_xor(dot, m, 64);
            ss  += __shfl_xor(ss,  m, 64);
        }
        const int jj = (tbase + k) % (1 + NNEG);
        const float logit = dot * rsqrtf(ss) * lsc[k] * SQRT_D;
        const float z  = (jj == 0) ? logit : -logit;
        const float ls = fminf(z, 0.0f) - log1pf(__expf(-fabsf(z)));   // stable log_sigmoid
        wacc += (jj == 0) ? ls * (1.0f / BB) : ls * (1.0f / (BB * NNEG));
    }
    if (lane == 0) s_red[wave] = wacc;
    __syncthreads();
    if (tid == 0) {
        float tot = s_red[0] + s_red[1] + s_red[2] + s_red[3];
        atomicAdd(out, -tot);
    }
}

extern "C" void kernel_launch(void* const* d_in, const int* in_sizes, int n_in,
                              void* d_out, int out_size, void* d_ws, size_t ws_size,
                              hipStream_t stream) {
    (void)in_sizes; (void)n_in; (void)out_size; (void)ws_size;
    const int*   input_ids    = (const int*)  d_in[0];
    const int*   target_ids   = (const int*)  d_in[1];
    const int*   neg_ids      = (const int*)  d_in[2];
    const float* W_in         = (const float*)d_in[3];
    const float* W_out        = (const float*)d_in[4];
    const float* W_hidden     = (const float*)d_in[5];
    const float* W_gate       = (const float*)d_in[6];
    const float* W_ff_out     = (const float*)d_in[7];
    const float* hidden_scale = (const float*)d_in[8];
    const float* gate_scale   = (const float*)d_in[9];
    const float* logit_scale  = (const float*)d_in[10];
    float* out = (float*)d_out;

    // ws layout (floats), all 16B-aligned where vector-accessed
    float* whT   = (float*)d_ws;          // 32*170*4  = 21760
    float* wgT   = whT + 21760;           // 21760
    float* wfT   = wgT + 21760;           // 43*128*4  = 22016
    float* inv_h = wfT + 22016;           // 170
    float* inv_g = inv_h + DI;            // 170
    float* inv_f = inv_g + DI;            // 170

    prep_kernel<<<108, 256, 0, stream>>>(W_hidden, W_gate, W_ff_out,
                                         whT, wgT, wfT,
                                         inv_h, inv_g, inv_f, out);
    main_kernel<<<NBLK, 256, 0, stream>>>(input_ids, target_ids, neg_ids,
                                          W_in, W_out, whT, wgT, wfT,
                                          hidden_scale, gate_scale, logit_scale,
                                          inv_h, inv_g, inv_f, out);
}